// Round 9
// baseline (129.649 us; speedup 1.0000x reference)
//
#include <hip/hip_runtime.h>
#include <math.h>

#define BLK 256

typedef __attribute__((ext_vector_type(8))) short s16x8;
typedef __attribute__((ext_vector_type(16))) float f32x16;

__device__ __forceinline__ float b2f(unsigned short h) {
    union { unsigned u; float f; } x; x.u = ((unsigned)h) << 16; return x.f;
}
__device__ __forceinline__ unsigned short f2b(float f) {
    union { float f; unsigned u; } x; x.f = f;
    unsigned r = x.u + 0x7fffu + ((x.u >> 16) & 1u);
    return (unsigned short)(r >> 16);
}
__device__ __forceinline__ unsigned pack2(float a, float b) {
    return (unsigned)f2b(a) | ((unsigned)f2b(b) << 16);
}

#define SITE(i, j) (peps + (size_t)((i) * 4 + (j)) * 2 * 1296)

// ws layout per batch (shorts), stride 11616 (23232 B, 16B-aligned records):
//  E0R@0 [216][8] | T11@1728 [36][56] | T12@3744 | T21@5760 | EBT@7776
//  T10@9792 [36][16] | T20@10368 | T13@10944 [6][56] | NT@11280
#define WSTRIDE 11616

// ======================= setup kernel (= round 8, unchanged) ================
__global__ __launch_bounds__(BLK, 4)
void peps_setup(const float* __restrict__ inputs,
                const float* __restrict__ peps,
                unsigned short* __restrict__ wsp)
{
    __shared__ unsigned short ESb[216 * 24]; // chain env bf16; bands A0=0 B0=6 A3=12 B3=18
    __shared__ float CTs[936];               // chain tiles fp32
    __shared__ float E0f[1296];
    __shared__ float EBf[1296];
    __shared__ float xs[32];

    const int b = blockIdx.x, tid = threadIdx.x;
    unsigned short* Wb = wsp + (size_t)b * WSTRIDE;

    if (tid < 32) xs[tid] = inputs[b * 32 + tid] * 100.0f;  // const rescale, absorbed by final norm
    __syncthreads();

    auto tile36 = [&](unsigned short* dst, const float* s, float x0, float x1) {
        unsigned* g = (unsigned*)dst;
        for (int idx = tid; idx < 1008; idx += BLK) {
            int n = idx / 28, k2 = idx % 28, k = 2 * k2;
            unsigned pk = 0;
            if (k < 36) {
                int ga = (k/6)*216 + (k%6) + (n/6)*6 + (n%6)*36;
                int gb = ((k+1)/6)*216 + ((k+1)%6) + (n/6)*6 + (n%6)*36;
                pk = pack2(x0*s[ga] + x1*s[ga+1296], x0*s[gb] + x1*s[gb+1296]);
            }
            g[idx] = pk;
        }
    };

    // ---- ph1: chain tiles + S0 inits (bf16) + small tiles ----
    for (int idx = tid; idx < 216; idx += BLK) {
        int x = idx/36, d = (idx/6)%6, r = idx%6;
        int g0 = x + d*6 + r*36, g3 = x + d*216 + r*36;
        CTs[idx]       = xs[2] *SITE(0,1)[g0] + xs[3] *SITE(0,1)[g0+1296];
        CTs[216 + idx] = xs[4] *SITE(0,2)[g0] + xs[5] *SITE(0,2)[g0+1296];
        CTs[432 + idx] = xs[26]*SITE(3,1)[g3] + xs[27]*SITE(3,1)[g3+1296];
        CTs[648 + idx] = xs[28]*SITE(3,2)[g3] + xs[29]*SITE(3,2)[g3+1296];
    }
    for (int idx = tid; idx < 36; idx += BLK) {
        int x = idx/6, d = idx%6;
        CTs[864 + idx] = xs[6] *SITE(0,3)[x + d*6]   + xs[7] *SITE(0,3)[x + d*6 + 1296];
        CTs[900 + idx] = xs[30]*SITE(3,3)[x + d*216] + xs[31]*SITE(3,3)[x + d*216 + 1296];
        int u = x, r = d;
        ESb[u*24 + 0  + r] = f2b(xs[0] *SITE(0,0)[r*36 + u*6]   + xs[1] *SITE(0,0)[r*36 + u*6 + 1296]);
        ESb[u*24 + 12 + r] = f2b(xs[24]*SITE(3,0)[u*216 + r*36] + xs[25]*SITE(3,0)[u*216 + r*36 + 1296]);
    }
    {   // T10, T20 (K6 records [36][16], k>=6 zero)
        unsigned* g10 = (unsigned*)(Wb + 9792);
        unsigned* g20 = (unsigned*)(Wb + 10368);
        const float *s10 = SITE(1,0), *s20 = SITE(2,0);
        for (int idx = tid; idx < 288; idx += BLK) {
            int n = idx/8, k2 = idx%8, k = 2*k2;
            unsigned a = 0, c = 0;
            if (k < 6) {
                int ga = k*216 + (n/6)*6 + (n%6)*36;
                int gb = (k+1)*216 + (n/6)*6 + (n%6)*36;
                a = pack2(xs[8] *s10[ga] + xs[9] *s10[ga+1296], xs[8] *s10[gb] + xs[9] *s10[gb+1296]);
                c = pack2(xs[16]*s20[ga] + xs[17]*s20[ga+1296], xs[16]*s20[gb] + xs[17]*s20[gb+1296]);
            }
            g10[idx] = a; g20[idx] = c;
        }
        // T13, NT (N6 records [6][56], k>=36 zero)
        unsigned* g13 = (unsigned*)(Wb + 10944);
        unsigned* gnt = (unsigned*)(Wb + 11280);
        const float *s13 = SITE(1,3), *snt = SITE(2,3);
        for (int idx = tid; idx < 168; idx += BLK) {
            int n = idx/28, k2 = idx%28, k = 2*k2;
            unsigned a = 0, c = 0;
            if (k < 36) {
                int ga = (k/6)*216 + (k%6) + n*6;
                int gb = ((k+1)/6)*216 + ((k+1)%6) + n*6;
                int gc = (k/6)*216 + (k%6)*6 + n;
                int gd = ((k+1)/6)*216 + ((k+1)%6)*6 + n;
                a = pack2(xs[14]*s13[ga] + xs[15]*s13[ga+1296], xs[14]*s13[gb] + xs[15]*s13[gb+1296]);
                c = pack2(xs[22]*snt[gc] + xs[23]*snt[gc+1296], xs[22]*snt[gd] + xs[23]*snt[gd+1296]);
            }
            g13[idx] = a; gnt[idx] = c;
        }
    }
    __syncthreads();

    // ---- ph2: chain step1 (M=6, bf16 env) + T11 ----
    for (int t = tid; t < 216; t += BLK) {
        int m = t/36, n = t%36;
        float a0 = 0.f, a3 = 0.f;
        #pragma unroll
        for (int k = 0; k < 6; ++k) {
            a0 = fmaf(b2f(ESb[m*24 + k]),      CTs[k*36 + n],       a0);
            a3 = fmaf(b2f(ESb[m*24 + 12 + k]), CTs[432 + k*36 + n], a3);
        }
        int row = m*6 + n/6;
        ESb[row*24 + 6  + n%6] = f2b(a0);
        ESb[row*24 + 18 + n%6] = f2b(a3);
    }
    tile36(Wb + 1728, SITE(1,1), xs[10], xs[11]);
    __syncthreads();

    // ---- ph3: chain step2 (M=36, bf16 env) + T12 ----
    for (int t = tid; t < 1296; t += BLK) {
        int m = t/36, n = t%36;
        float a0 = 0.f, a3 = 0.f;
        #pragma unroll
        for (int k = 0; k < 6; ++k) {
            a0 = fmaf(b2f(ESb[m*24 + 6  + k]), CTs[216 + k*36 + n], a0);
            a3 = fmaf(b2f(ESb[m*24 + 18 + k]), CTs[648 + k*36 + n], a3);
        }
        int row = m*6 + n/6;
        ESb[row*24 + n%6]      = f2b(a0);
        ESb[row*24 + 12 + n%6] = f2b(a3);
    }
    tile36(Wb + 3744, SITE(1,2), xs[12], xs[13]);
    __syncthreads();

    // ---- ph4: chain tails (M=216,K=6,N=6, bf16 env) + T21 ----
    for (int t = tid; t < 1296; t += BLK) {
        int m = t/6, n = t%6;
        float a0 = 0.f, a3 = 0.f;
        #pragma unroll
        for (int k = 0; k < 6; ++k) {
            a0 = fmaf(b2f(ESb[m*24 + k]),      CTs[864 + k*6 + n], a0);
            a3 = fmaf(b2f(ESb[m*24 + 12 + k]), CTs[900 + k*6 + n], a3);
        }
        E0f[((m%36)*6 + n)*6 + m/36]    = a0;   // E0 [(d1d2d3)][d0]
        EBf[(m/6)*36 + (m%6)*6 + n]     = a3;   // EB [(d0d1)][(d2d3)]
    }
    tile36(Wb + 5760, SITE(2,1), xs[18], xs[19]);
    __syncthreads();

    // ---- ph5: E0 image rows [216][8] + EBt tile [36][56] ----
    {
        unsigned* ge = (unsigned*)(Wb + 0);
        for (int idx = tid; idx < 864; idx += BLK) {
            int m = idx/4, c2 = idx%4;
            ge[idx] = (c2 < 3) ? pack2(E0f[m*6 + 2*c2], E0f[m*6 + 2*c2 + 1]) : 0u;
        }
        unsigned* gb2 = (unsigned*)(Wb + 7776);
        for (int idx = tid; idx < 1008; idx += BLK) {
            int n = idx/28, k2 = idx%28, k = 2*k2;
            gb2[idx] = (k < 36) ? pack2(EBf[k*36 + n], EBf[(k+1)*36 + n]) : 0u;
        }
    }
}

// ======================= main kernel =======================
// ROUND-6 MFMA configuration VERBATIM (the passing one): A=env (lane->m),
// B=tile (lane->n, rows nt*4+col), C/D: col(lane)=n, row(regs)=m with
// row=(reg&3)+8*(reg>>2)+4*(lane>>5) [m74/m101]. Scalar f2b scatters with
// round-6 target formulas. Only the tile builds are replaced by ws DMA.

#define MFMA_PHASE(NKB, NNT, TB, TSTR) do {                                    \
    s16x8 _bf[NNT][NKB];                                                       \
    _Pragma("unroll") for (int nt = 0; nt < NNT; ++nt)                         \
    _Pragma("unroll") for (int kb = 0; kb < NKB; ++kb)                         \
        _bf[nt][kb] = *(const s16x8*)&(TB)[(nt*4 + col)*(TSTR) + kb*16 + q*8]; \
    _Pragma("unroll") for (int i = 0; i < 2; ++i) {                            \
        if (i < nmt) {                                                         \
            int mt = wid + 4*i; int m0 = (mt == 6) ? 184 : mt*32;              \
            s16x8 _av[NKB];                                                    \
            _Pragma("unroll") for (int kb = 0; kb < NKB; ++kb)                 \
                _av[kb] = *(const s16x8*)&Ebuf[(m0 + col)*56 + kb*16 + q*8];   \
            _Pragma("unroll") for (int nt = 0; nt < NNT; ++nt)                 \
            _Pragma("unroll") for (int kb = 0; kb < NKB; ++kb)                 \
                acc[i][nt] = __builtin_amdgcn_mfma_f32_32x32x16_bf16(          \
                    _av[kb], _bf[nt][kb], acc[i][nt], 0, 0, 0);                \
        } } } while (0)

#define SCATTER(NNT, NLIM, PUT) do {                                           \
    _Pragma("unroll") for (int i = 0; i < 2; ++i) {                            \
      if (i < nmt) {                                                           \
        int mt = wid + 4*i; int m0 = (mt == 6) ? 184 : mt*32;                  \
        _Pragma("unroll") for (int nt = 0; nt < NNT; ++nt) {                   \
            int n = nt*4 + col;                                                \
            if ((NNT == 2 && nt == 1 && n < 32) || n >= NLIM) continue;        \
            _Pragma("unroll") for (int r = 0; r < 16; ++r) {                   \
                int m = m0 + (r&3) + 8*(r>>2) + 4*q;                           \
                if (mt == 6 && m < 192) continue;                              \
                float v = acc[i][nt][r];                                       \
                PUT;                                                           \
            } } } } } while (0)

#define ACC0() do {                                                            \
    _Pragma("unroll") for (int i = 0; i < 2; ++i)                              \
    _Pragma("unroll") for (int nt = 0; nt < 2; ++nt)                           \
    _Pragma("unroll") for (int r = 0; r < 16; ++r) acc[i][nt][r] = 0.f;        \
    } while (0)

__global__ __launch_bounds__(BLK, 4)
void peps_main(const float* __restrict__ inputs,
               const float* __restrict__ pepsc,
               const unsigned short* __restrict__ wsp,
               float* __restrict__ out)
{
    // LDS ~34.8 KB -> 4 blocks/CU; grid 1024 = one round.
    __shared__ __align__(16) unsigned short Ebuf[216 * 56];  // env bf16 [m][56]
    __shared__ __align__(16) unsigned short Tbuf[36 * 56];   // tile [n][56]
    __shared__ __align__(16) unsigned short Tk6[36 * 16];    // K6 tile [n][16]
    __shared__ __align__(16) float T1f[1296];
    __shared__ float red[52];

    const int b   = blockIdx.x;
    const int tid = threadIdx.x;
    const int lid = tid & 63;
    const int q   = lid >> 5;
    const int col = lid & 31;
    const int wid = tid >> 6;
    const int nmt = (wid < 3) ? 2 : 1;

    const unsigned short* Wb = wsp + (size_t)b * WSTRIDE;
    f32x16 acc[2][2];
    const float4 z4 = make_float4(0.f, 0.f, 0.f, 0.f);

    // ---- init: prefetch E0 image + T11 + T10; zero env cols 8..55 ----
    float4 pE = z4, pT = z4, pK = z4;
    if (tid < 216) pE = *(const float4*)(Wb + tid * 8);          // E0R row (cols 0..7)
    if (tid < 252) pT = *(const float4*)(Wb + 1728 + tid * 8);   // T11
    if (tid < 72)  pK = *(const float4*)(Wb + 9792 + tid * 8);   // T10
    for (int idx = tid; idx < 1296; idx += BLK) {
        int m = idx / 6, c = idx % 6;
        *(float4*)((char*)Ebuf + m * 112 + 16 + c * 16) = z4;    // cols 8..55
    }
    if (tid < 216) *(float4*)((char*)Ebuf + tid * 112) = pE;
    if (tid < 252) *(float4*)((char*)Tbuf + tid * 16) = pT;
    if (tid < 72)  *(float4*)((char*)Tk6  + tid * 16) = pK;
    __syncthreads();

    // ================= row 1 =================
    ACC0();
    if (tid < 252) pT = *(const float4*)(Wb + 3744 + tid * 8);   // prefetch T12
    if (tid < 72)  pK = *(const float4*)(Wb + 10368 + tid * 8);  // prefetch T20
    MFMA_PHASE(1, 2, Tk6, 16);                                   // P5: j=0 (K6, T10)
    __syncthreads();
    SCATTER(2, 36, Ebuf[((m%36)*6 + n/6)*56 + (m/36)*6 + n%6] = f2b(v));  // P6
    if (tid < 72) *(float4*)((char*)Tk6 + tid * 16) = pK;        // T20 -> Tk6
    __syncthreads();
    ACC0();
    MFMA_PHASE(3, 2, Tbuf, 56);                                  // P7: j=1 (T11)
    __syncthreads();
    SCATTER(2, 36, Ebuf[((m%36)*6 + n/6)*56 + (m/36)*6 + n%6] = f2b(v));  // P8
    if (tid < 252) *(float4*)((char*)Tbuf + tid * 16) = pT;      // T12 -> Tbuf
    if (tid < 42)  pT = *(const float4*)(Wb + 10944 + tid * 8);  // prefetch T13
    __syncthreads();
    ACC0();
    MFMA_PHASE(3, 2, Tbuf, 56);                                  // P9: j=2 (T12)
    __syncthreads();
    SCATTER(2, 36, Ebuf[((m%36)*6 + n/6)*56 + (m/36)*6 + n%6] = f2b(v));  // P10
    if (tid < 42) *(float4*)((char*)Tbuf + tid * 16) = pT;       // T13 rows 0..5
    if (tid < 252) pT = *(const float4*)(Wb + 5760 + tid * 8);   // prefetch T21
    __syncthreads();
    ACC0();
    MFMA_PHASE(3, 1, Tbuf, 56);                                  // P11: j=3 (T13, N6)
    __syncthreads();
    SCATTER(1, 6, Ebuf[((m%36)*6 + n)*56 + m/36] = f2b(v));      // P12: env_top
    if (tid < 252) *(float4*)((char*)Tbuf + tid * 16) = pT;      // T21 -> Tbuf
    if (tid < 252) pT = *(const float4*)(Wb + 7776 + tid * 8);   // prefetch EBt
    __syncthreads();

    // ================= row 2 =================
    ACC0();
    MFMA_PHASE(1, 2, Tk6, 16);                                   // P13: j=0 (K6, T20)
    __syncthreads();
    SCATTER(2, 36, Ebuf[((m%36)*6 + n/6)*56 + (m/36)*6 + n%6] = f2b(v));  // P14
    __syncthreads();
    ACC0();
    MFMA_PHASE(3, 2, Tbuf, 56);                                  // P15: j=1 (T21)
    __syncthreads();
    SCATTER(2, 36, Ebuf[((m/6)*6 + n%6)*56 + (m%6)*6 + n/6] = f2b(v));    // P16: S_pre
    if (tid < 252) *(float4*)((char*)Tbuf + tid * 16) = pT;      // EBt -> Tbuf
    if (tid < 42)  pT = *(const float4*)(Wb + 11280 + tid * 8);  // prefetch NT
    __syncthreads();
    ACC0();
    MFMA_PHASE(3, 2, Tbuf, 56);                                  // P17: R = S_pre x EB
    __syncthreads();
    SCATTER(2, 36, Ebuf[((m/36)*36 + (m%6)*6 + n/6)*56 + ((m/6)%6)*6 + n%6] = f2b(v)); // P18
    if (tid < 42) *(float4*)((char*)Tbuf + tid * 16) = pT;       // NT rows 0..5
    __syncthreads();
    ACC0();
    MFMA_PHASE(3, 1, Tbuf, 56);                                  // P19: T1 (NT, N6)
    SCATTER(1, 6, T1f[m*6 + n] = v);
    __syncthreads();

    // ---- P20: out[o] = sum T1 * (x20*C0 + x21*C1), coalesced over pepsc ----
    const float x20 = inputs[b * 32 + 20] * 100.0f;
    const float x21 = inputs[b * 32 + 21] * 100.0f;
    float part[10];
    #pragma unroll
    for (int o = 0; o < 10; ++o) part[o] = 0.f;
    for (int c = tid; c < 1296; c += BLK) {
        int u2 = c / 216, r2 = (c / 36) % 6, d2 = (c / 6) % 6, r1 = c % 6;
        float t1 = T1f[u2*216 + r1*36 + d2*6 + r2];
        #pragma unroll
        for (int o = 0; o < 10; ++o) {
            float c0 = pepsc[o * 1296 + c];
            float c1 = pepsc[(10 + o) * 1296 + c];
            part[o] = fmaf(t1, x20 * c0 + x21 * c1, part[o]);
        }
    }
    #pragma unroll
    for (int off = 32; off >= 1; off >>= 1)
        #pragma unroll
        for (int o = 0; o < 10; ++o)
            part[o] += __shfl_down(part[o], off, 64);
    if (lid == 0) {
        #pragma unroll
        for (int o = 0; o < 10; ++o) red[wid * 10 + o] = part[o];
    }
    __syncthreads();
    if (tid < 10)
        red[40 + tid] = red[tid] + red[10 + tid] + red[20 + tid] + red[30 + tid];
    __syncthreads();
    if (tid == 0) {
        float n2 = 0.f;
        #pragma unroll
        for (int o = 0; o < 10; ++o) n2 += red[40 + o] * red[40 + o];
        red[50] = 1.0f / sqrtf(n2);
    }
    __syncthreads();
    if (tid < 10) out[b * 10 + tid] = red[40 + tid] * red[50];
}

extern "C" void kernel_launch(void* const* d_in, const int* in_sizes, int n_in,
                              void* d_out, int out_size, void* d_ws, size_t ws_size,
                              hipStream_t stream) {
    const float* inputs = (const float*)d_in[0];   // (B,4,4,2) f32
    const float* peps   = (const float*)d_in[1];   // (4,4,2,6,6,6,6) f32
    const float* pepsc  = (const float*)d_in[2];   // (2,10,6,6,6,6) f32
    float* outp = (float*)d_out;                   // (B,10) f32
    unsigned short* W = (unsigned short*)d_ws;     // needs B*23232 B (~23.8 MB)
    const int B = in_sizes[0] / 32;
    peps_setup<<<dim3(B), dim3(BLK), 0, stream>>>(inputs, peps, W);
    peps_main<<<dim3(B), dim3(BLK), 0, stream>>>(inputs, pepsc, W, outp);
}

// Round 10
// 120.349 us; speedup vs baseline: 1.0773x; 1.0773x over previous
//
#include <hip/hip_runtime.h>
#include <math.h>

#define BLK 256

typedef __attribute__((ext_vector_type(8))) short s16x8;
typedef __attribute__((ext_vector_type(16))) float f32x16;

__device__ __forceinline__ float b2f(unsigned short h) {
    union { unsigned u; float f; } x; x.u = ((unsigned)h) << 16; return x.f;
}
__device__ __forceinline__ unsigned short f2b(float f) {
    union { float f; unsigned u; } x; x.f = f;
    unsigned r = x.u + 0x7fffu + ((x.u >> 16) & 1u);
    return (unsigned short)(r >> 16);
}

#define SITE(i, j) (peps + (size_t)((i) * 4 + (j)) * 2 * 1296)

// ======================= MFMA config (round-6 verbatim, proven) =============
// A=env (lane->m), B=tile (lane->n via rows nt*4+col), C/D: col(lane)=n,
// row=(reg&3)+8*(reg>>2)+4*(lane>>5) [m74/m101]. Wave w owns Mtiles {w,w+4}
// (w<3) / {3}; Mtile6 base 184, dedup keeps m>=192. Ntile1 keeps n>=32.

#define MFMA_PHASE(NKB, NNT, TB, TSTR) do {                                    \
    s16x8 _bf[NNT][NKB];                                                       \
    _Pragma("unroll") for (int nt = 0; nt < NNT; ++nt)                         \
    _Pragma("unroll") for (int kb = 0; kb < NKB; ++kb)                         \
        _bf[nt][kb] = *(const s16x8*)&(TB)[(nt*4 + col)*(TSTR) + kb*16 + q*8]; \
    _Pragma("unroll") for (int i = 0; i < 2; ++i) {                            \
        if (i < nmt) {                                                         \
            int mt = wid + 4*i; int m0 = (mt == 6) ? 184 : mt*32;              \
            s16x8 _av[NKB];                                                    \
            _Pragma("unroll") for (int kb = 0; kb < NKB; ++kb)                 \
                _av[kb] = *(const s16x8*)&Ebuf[(m0 + col)*56 + kb*16 + q*8];   \
            _Pragma("unroll") for (int nt = 0; nt < NNT; ++nt)                 \
            _Pragma("unroll") for (int kb = 0; kb < NKB; ++kb)                 \
                acc[i][nt] = __builtin_amdgcn_mfma_f32_32x32x16_bf16(          \
                    _av[kb], _bf[nt][kb], acc[i][nt], 0, 0, 0);                \
        } } } while (0)

#define SCATTER(NNT, NLIM, PUT) do {                                           \
    _Pragma("unroll") for (int i = 0; i < 2; ++i) {                            \
      if (i < nmt) {                                                           \
        int mt = wid + 4*i; int m0 = (mt == 6) ? 184 : mt*32;                  \
        _Pragma("unroll") for (int nt = 0; nt < NNT; ++nt) {                   \
            int n = nt*4 + col;                                                \
            if ((NNT == 2 && nt == 1 && n < 32) || n >= NLIM) continue;        \
            _Pragma("unroll") for (int r = 0; r < 16; ++r) {                   \
                int m = m0 + (r&3) + 8*(r>>2) + 4*q;                           \
                if (mt == 6 && m < 192) continue;                              \
                float v = acc[i][nt][r];                                       \
                PUT;                                                           \
            } } } } } while (0)

#define ACC0() do {                                                            \
    _Pragma("unroll") for (int i = 0; i < 2; ++i)                              \
    _Pragma("unroll") for (int nt = 0; nt < 2; ++nt)                           \
    _Pragma("unroll") for (int r = 0; r < 16; ++r) acc[i][nt][r] = 0.f;        \
    } while (0)

__global__ __launch_bounds__(BLK, 4)
void peps_fused(const float* __restrict__ inputs,
                const float* __restrict__ peps,
                const float* __restrict__ pepsc,
                float* __restrict__ out)
{
    // LDS 38.6 KB -> 4 blocks/CU; grid 1024 = exactly one round.
    // Slot plan: TA holds T11 (P1..P7), then T12 (P8..P9), then T21 (P10..P15).
    // TBt holds EBT bf16 (written directly at the chain tail P4, read P17).
    // CTf holds chain tiles (P1..P4), then T13 (P6..P11), then NT (P12..P19).
    // T1f overlays Ebuf after the last MFMA (P19a barrier P19b).
    __shared__ __align__(16) unsigned short Ebuf[216 * 56];  // env bf16 [m][56]
    __shared__ __align__(16) unsigned short TA[36 * 56];     // rotating big tile
    __shared__ __align__(16) unsigned short TBt[36 * 56];    // EBT tile
    __shared__ __align__(16) unsigned short Tk6[2 * 36 * 16];// T10, T20
    __shared__ __align__(16) float CTf[936];                 // chain tiles / T13 / NT
    __shared__ float xs[32];
    __shared__ float red[52];

    const int b   = blockIdx.x;
    const int tid = threadIdx.x;
    const int lid = tid & 63;
    const int q   = lid >> 5;
    const int col = lid & 31;
    const int wid = tid >> 6;
    const int nmt = (wid < 3) ? 2 : 1;

    unsigned short* T13p = (unsigned short*)CTf;  // valid rows 0..5; stale rows
                                                  // 6..31 feed discarded n-cols
    float* T1f = (float*)Ebuf;                    // alive only after P19a

    f32x16 acc[2][2];

    // ---- P0: zero Ebuf (k-pads 36..55 stay 0 -> inert vs zero-padded B);
    //          x scaled by 100 (constant rescale, absorbed by final norm).
    {
        uint4* ez = (uint4*)Ebuf;
        const uint4 z = make_uint4(0u, 0u, 0u, 0u);
        for (int i2 = tid; i2 < 1512; i2 += BLK) ez[i2] = z;
        if (tid < 32) xs[tid] = inputs[b * 32 + tid] * 100.0f;
    }
    __syncthreads();

    // ---- P1: ALL early weight gathers in one deep-MLP phase --------------
    // chain tiles (fp32), S0 inits (bf16 bands 6/18), T10/T20, T11, TBt pads.
    for (int idx = tid; idx < 216; idx += BLK) {
        int x = idx/36, d = (idx/6)%6, r = idx%6;
        int g0 = x + d*6 + r*36, g3 = x + d*216 + r*36;
        CTf[idx]       = xs[2] *SITE(0,1)[g0] + xs[3] *SITE(0,1)[g0+1296];
        CTf[216 + idx] = xs[4] *SITE(0,2)[g0] + xs[5] *SITE(0,2)[g0+1296];
        CTf[432 + idx] = xs[26]*SITE(3,1)[g3] + xs[27]*SITE(3,1)[g3+1296];
        CTf[648 + idx] = xs[28]*SITE(3,2)[g3] + xs[29]*SITE(3,2)[g3+1296];
    }
    for (int idx = tid; idx < 36; idx += BLK) {
        int x = idx/6, d = idx%6;
        CTf[864 + idx] = xs[6] *SITE(0,3)[x + d*6]   + xs[7] *SITE(0,3)[x + d*6 + 1296];
        CTf[900 + idx] = xs[30]*SITE(3,3)[x + d*216] + xs[31]*SITE(3,3)[x + d*216 + 1296];
        int u = x, r = d;
        Ebuf[u*56 + 6  + r] = f2b(xs[0] *SITE(0,0)[r*36 + u*6]   + xs[1] *SITE(0,0)[r*36 + u*6 + 1296]);
        Ebuf[u*56 + 18 + r] = f2b(xs[24]*SITE(3,0)[u*216 + r*36] + xs[25]*SITE(3,0)[u*216 + r*36 + 1296]);
    }
    {   // T10 / T20 (K6 tiles [36][16], k>=6 zero)
        const float *s10 = SITE(1,0), *s20 = SITE(2,0);
        for (int idx = tid; idx < 576; idx += BLK) {
            int n = idx/16, k = idx%16;
            float v0 = 0.f, v1 = 0.f;
            if (k < 6) {
                int g = k*216 + (n/6)*6 + (n%6)*36;
                v0 = xs[8] *s10[g] + xs[9] *s10[g+1296];
                v1 = xs[16]*s20[g] + xs[17]*s20[g+1296];
            }
            Tk6[n*16 + k]       = f2b(v0);
            Tk6[576 + n*16 + k] = f2b(v1);
        }
    }
    {   // T11 -> TA  ([36][48 valid], k>=36 zero)
        const float* s = SITE(1,1);
        for (int idx = tid; idx < 1728; idx += BLK) {
            int n = idx/48, k = idx%48;
            float v = 0.f;
            if (k < 36) {
                int g = (k/6)*216 + (k%6) + (n/6)*6 + (n%6)*36;
                v = xs[10]*s[g] + xs[11]*s[g+1296];
            }
            TA[n*56 + k] = f2b(v);
        }
    }
    for (int idx = tid; idx < 432; idx += BLK) {   // TBt k-pads 36..47 zero
        int n = idx/12, k = 36 + idx%12;
        TBt[n*56 + k] = 0;
    }
    __syncthreads();

    // ---- P2: chain step1 (M=6): band6->12 (T01); band18->24 (T31) --------
    for (int t2 = tid; t2 < 216; t2 += BLK) {
        int m = t2/36, n = t2%36;
        float a0 = 0.f, a3 = 0.f;
        #pragma unroll
        for (int k = 0; k < 6; ++k) {
            a0 = fmaf(b2f(Ebuf[m*56 + 6  + k]), CTf[k*36 + n],       a0);
            a3 = fmaf(b2f(Ebuf[m*56 + 18 + k]), CTf[432 + k*36 + n], a3);
        }
        int o = (m*6 + n/6)*56 + n%6;
        Ebuf[o + 12] = f2b(a0);
        Ebuf[o + 24] = f2b(a3);
    }
    __syncthreads();

    // ---- P3: chain step2 (M=36): band12->6 (T02); band24->18 (T32) -------
    for (int t2 = tid; t2 < 1296; t2 += BLK) {
        int m = t2/36, n = t2%36;
        float a0 = 0.f, a3 = 0.f;
        #pragma unroll
        for (int k = 0; k < 6; ++k) {
            a0 = fmaf(b2f(Ebuf[m*56 + 12 + k]), CTf[216 + k*36 + n], a0);
            a3 = fmaf(b2f(Ebuf[m*56 + 24 + k]), CTf[648 + k*36 + n], a3);
        }
        int o = (m*6 + n/6)*56 + n%6;
        Ebuf[o + 6]  = f2b(a0);
        Ebuf[o + 18] = f2b(a3);
    }
    __syncthreads();

    // ---- P4: chain tails (M=216,K=6,N=6): band6 -> E0 (Ebuf cols 0..5);
    //          band18 -> EBT bf16 tile directly (f2b(a3), bit-same as r6).
    for (int t2 = tid; t2 < 1296; t2 += BLK) {
        int m = t2/6, n = t2%6;
        float a0 = 0.f, a3 = 0.f;
        #pragma unroll
        for (int k = 0; k < 6; ++k) {
            a0 = fmaf(b2f(Ebuf[m*56 + 6  + k]), CTf[864 + k*6 + n], a0);
            a3 = fmaf(b2f(Ebuf[m*56 + 18 + k]), CTf[900 + k*6 + n], a3);
        }
        Ebuf[((m % 36)*6 + n)*56 + m/36] = f2b(a0);        // E0 [(d1d2d3)][d0]
        TBt[((m % 6)*6 + n)*56 + m/6]    = f2b(a3);        // EBT [n=(d2d3)][k=(d0d1)]
    }
    __syncthreads();

    // ================= row 1 =================
    ACC0();
    MFMA_PHASE(1, 2, Tk6, 16);                                   // P5: j=0 (T10)
    __syncthreads();
    SCATTER(2, 36, Ebuf[((m%36)*6 + n/6)*56 + (m/36)*6 + n%6] = f2b(v));  // P6
    {   // build T13 -> CTf region (rows 0..5, k-pads zero)
        const float* s = SITE(1,3);
        for (int idx = tid; idx < 288; idx += BLK) {
            int n = idx/48, k = idx%48;
            float v = 0.f;
            if (k < 36) { int g = (k/6)*216 + (k%6) + n*6; v = xs[14]*s[g] + xs[15]*s[g+1296]; }
            T13p[n*56 + k] = f2b(v);
        }
    }
    __syncthreads();
    ACC0();
    MFMA_PHASE(3, 2, TA, 56);                                    // P7: j=1 (T11)
    __syncthreads();
    SCATTER(2, 36, Ebuf[((m%36)*6 + n/6)*56 + (m/36)*6 + n%6] = f2b(v));  // P8
    {   // build T12 -> TA (T11 dead)
        const float* s = SITE(1,2);
        for (int idx = tid; idx < 1728; idx += BLK) {
            int n = idx/48, k = idx%48;
            float v = 0.f;
            if (k < 36) { int g = (k/6)*216 + (k%6) + (n/6)*6 + (n%6)*36; v = xs[12]*s[g] + xs[13]*s[g+1296]; }
            TA[n*56 + k] = f2b(v);
        }
    }
    __syncthreads();
    ACC0();
    MFMA_PHASE(3, 2, TA, 56);                                    // P9: j=2 (T12)
    __syncthreads();
    SCATTER(2, 36, Ebuf[((m%36)*6 + n/6)*56 + (m/36)*6 + n%6] = f2b(v));  // P10
    {   // build T21 -> TA (T12 dead)
        const float* s = SITE(2,1);
        for (int idx = tid; idx < 1728; idx += BLK) {
            int n = idx/48, k = idx%48;
            float v = 0.f;
            if (k < 36) { int g = (k/6)*216 + (k%6) + (n/6)*6 + (n%6)*36; v = xs[18]*s[g] + xs[19]*s[g+1296]; }
            TA[n*56 + k] = f2b(v);
        }
    }
    __syncthreads();
    ACC0();
    MFMA_PHASE(3, 1, T13p, 56);                                  // P11: j=3 (T13, N6)
    __syncthreads();
    SCATTER(1, 6, Ebuf[((m%36)*6 + n)*56 + m/36] = f2b(v));      // P12: env_top
    {   // build NT -> CTf region (T13 dead)
        const float* s = SITE(2,3);
        for (int idx = tid; idx < 288; idx += BLK) {
            int n = idx/48, k = idx%48;
            float v = 0.f;
            if (k < 36) { int g = (k/6)*216 + (k%6)*6 + n; v = xs[22]*s[g] + xs[23]*s[g+1296]; }
            T13p[n*56 + k] = f2b(v);
        }
    }
    __syncthreads();

    // ================= row 2 =================
    ACC0();
    MFMA_PHASE(1, 2, (Tk6 + 576), 16);                           // P13: j=0 (T20)
    __syncthreads();
    SCATTER(2, 36, Ebuf[((m%36)*6 + n/6)*56 + (m/36)*6 + n%6] = f2b(v));  // P14
    __syncthreads();
    ACC0();
    MFMA_PHASE(3, 2, TA, 56);                                    // P15: j=1 (T21)
    __syncthreads();
    SCATTER(2, 36, Ebuf[((m/6)*6 + n%6)*56 + (m%6)*6 + n/6] = f2b(v));    // P16: S_pre
    __syncthreads();
    ACC0();
    MFMA_PHASE(3, 2, TBt, 56);                                   // P17: R = S_pre x EB
    __syncthreads();
    SCATTER(2, 36, Ebuf[((m/36)*36 + (m%6)*6 + n/6)*56 + ((m/6)%6)*6 + n%6] = f2b(v)); // P18
    __syncthreads();
    ACC0();
    MFMA_PHASE(3, 1, T13p, 56);                                  // P19a: T1 (NT, N6)
    __syncthreads();   // all Ebuf frag reads done before T1f overlays it
    SCATTER(1, 6, T1f[m*6 + n] = v);                             // P19b
    __syncthreads();

    // ---- P20: out[o] = sum T1 * (x20*C0 + x21*C1), coalesced over pepsc ----
    float part[10];
    #pragma unroll
    for (int o = 0; o < 10; ++o) part[o] = 0.f;
    for (int c = tid; c < 1296; c += BLK) {
        int u2 = c / 216, r2 = (c / 36) % 6, d2 = (c / 6) % 6, r1 = c % 6;
        float t1 = T1f[u2*216 + r1*36 + d2*6 + r2];
        #pragma unroll
        for (int o = 0; o < 10; ++o) {
            float c0 = pepsc[o * 1296 + c];
            float c1 = pepsc[(10 + o) * 1296 + c];
            part[o] = fmaf(t1, xs[20] * c0 + xs[21] * c1, part[o]);
        }
    }
    #pragma unroll
    for (int off = 32; off >= 1; off >>= 1)
        #pragma unroll
        for (int o = 0; o < 10; ++o)
            part[o] += __shfl_down(part[o], off, 64);
    if (lid == 0) {
        #pragma unroll
        for (int o = 0; o < 10; ++o) red[wid * 10 + o] = part[o];
    }
    __syncthreads();
    if (tid < 10)
        red[40 + tid] = red[tid] + red[10 + tid] + red[20 + tid] + red[30 + tid];
    __syncthreads();
    if (tid == 0) {
        float n2 = 0.f;
        #pragma unroll
        for (int o = 0; o < 10; ++o) n2 += red[40 + o] * red[40 + o];
        red[50] = 1.0f / sqrtf(n2);
    }
    __syncthreads();
    if (tid < 10) out[b * 10 + tid] = red[40 + tid] * red[50];
}

extern "C" void kernel_launch(void* const* d_in, const int* in_sizes, int n_in,
                              void* d_out, int out_size, void* d_ws, size_t ws_size,
                              hipStream_t stream) {
    const float* inputs = (const float*)d_in[0];   // (B,4,4,2) f32
    const float* peps   = (const float*)d_in[1];   // (4,4,2,6,6,6,6) f32
    const float* pepsc  = (const float*)d_in[2];   // (2,10,6,6,6,6) f32
    float* outp = (float*)d_out;                   // (B,10) f32
    const int B = in_sizes[0] / 32;
    peps_fused<<<dim3(B), dim3(BLK), 0, stream>>>(inputs, peps, pepsc, outp);
}

// Round 11
// 109.678 us; speedup vs baseline: 1.1821x; 1.0973x over previous
//
#include <hip/hip_runtime.h>
#include <math.h>

#define BLK 256

typedef __attribute__((ext_vector_type(8))) short s16x8;
typedef __attribute__((ext_vector_type(16))) float f32x16;

__device__ __forceinline__ float b2f(unsigned short h) {
    union { unsigned u; float f; } x; x.u = ((unsigned)h) << 16; return x.f;
}
__device__ __forceinline__ unsigned short f2b(float f) {
    union { float f; unsigned u; } x; x.f = f;
    unsigned r = x.u + 0x7fffu + ((x.u >> 16) & 1u);
    return (unsigned short)(r >> 16);
}

#define SITE(i, j) (peps + (size_t)((i) * 4 + (j)) * 2 * 1296)

// ======================= MFMA config (round-6 verbatim, proven) =============
// A=env (lane->m), B=tile (lane->n via rows nt*4+col), C/D: col(lane)=n,
// row=(reg&3)+8*(reg>>2)+4*(lane>>5) [m74/m101]. Wave w owns Mtiles {w,w+4}
// (w<3) / {3}; Mtile6 base 184, dedup keeps m>=192. Ntile1 keeps n>=32.
// Two batches (slots) per block: every phase runs slot 0 then slot 1; all
// weight loads are shared between slots.

#define MFMA_PHASE(S, NKB, NNT, TB, TSTR) do {                                 \
    const unsigned short* _Eb = Ebuf[S];                                       \
    s16x8 _bf[NNT][NKB];                                                       \
    _Pragma("unroll") for (int nt = 0; nt < NNT; ++nt)                         \
    _Pragma("unroll") for (int kb = 0; kb < NKB; ++kb)                         \
        _bf[nt][kb] = *(const s16x8*)&(TB)[(nt*4 + col)*(TSTR) + kb*16 + q*8]; \
    _Pragma("unroll") for (int i = 0; i < 2; ++i) {                            \
        if (i < nmt) {                                                         \
            int mt = wid + 4*i; int m0 = (mt == 6) ? 184 : mt*32;              \
            s16x8 _av[NKB];                                                    \
            _Pragma("unroll") for (int kb = 0; kb < NKB; ++kb)                 \
                _av[kb] = *(const s16x8*)&_Eb[(m0 + col)*56 + kb*16 + q*8];    \
            _Pragma("unroll") for (int nt = 0; nt < NNT; ++nt)                 \
            _Pragma("unroll") for (int kb = 0; kb < NKB; ++kb)                 \
                acc[S][i][nt] = __builtin_amdgcn_mfma_f32_32x32x16_bf16(       \
                    _av[kb], _bf[nt][kb], acc[S][i][nt], 0, 0, 0);             \
        } } } while (0)

// PUT uses (m, n, v) and may use EbS / T1S.
#define SCATTER(S, NNT, NLIM, PUT) do {                                        \
    unsigned short* EbS = Ebuf[S];                                             \
    float* T1S = (float*)Ebuf[S]; (void)EbS; (void)T1S;                        \
    _Pragma("unroll") for (int i = 0; i < 2; ++i) {                            \
      if (i < nmt) {                                                           \
        int mt = wid + 4*i; int m0 = (mt == 6) ? 184 : mt*32;                  \
        _Pragma("unroll") for (int nt = 0; nt < NNT; ++nt) {                   \
            int n = nt*4 + col;                                                \
            if ((NNT == 2 && nt == 1 && n < 32) || n >= NLIM) continue;        \
            _Pragma("unroll") for (int r = 0; r < 16; ++r) {                   \
                int m = m0 + (r&3) + 8*(r>>2) + 4*q;                           \
                if (mt == 6 && m < 192) continue;                              \
                float v = acc[S][i][nt][r];                                    \
                PUT;                                                           \
            } } } } } while (0)

#define ACC0() do {                                                            \
    _Pragma("unroll") for (int s2 = 0; s2 < 2; ++s2)                           \
    _Pragma("unroll") for (int i = 0; i < 2; ++i)                              \
    _Pragma("unroll") for (int nt = 0; nt < 2; ++nt)                           \
    _Pragma("unroll") for (int r = 0; r < 16; ++r) acc[s2][i][nt][r] = 0.f;    \
    } while (0)

__global__ __launch_bounds__(BLK, 2)
void peps_fused(const float* __restrict__ inputs,
                const float* __restrict__ peps,
                const float* __restrict__ pepsc,
                float* __restrict__ out)
{
    // LDS ~77.3 KB -> 2 blocks/CU; grid 512 -> all co-resident (1 round).
    __shared__ __align__(16) unsigned short Ebuf[2][216 * 56];  // env bf16 [m][56]
    __shared__ __align__(16) unsigned short TA[2][36 * 56];     // rotating big tile
    __shared__ __align__(16) unsigned short TBt[2][36 * 56];    // EBT tile
    __shared__ __align__(16) unsigned short Tk6[2][2 * 36 * 16];// T10, T20
    __shared__ __align__(16) float CTf[2][936];                 // chain tiles / T13 / NT
    __shared__ float xs[64];
    __shared__ float red[104];

    const int b0  = blockIdx.x * 2;
    const int tid = threadIdx.x;
    const int lid = tid & 63;
    const int q   = lid >> 5;
    const int col = lid & 31;
    const int wid = tid >> 6;
    const int nmt = (wid < 3) ? 2 : 1;

    f32x16 acc[2][2][2];

    // ---- P0: zero Ebuf (k-pads stay 0 forever), load x (scaled by 100:
    //          constant rescale, absorbed by the final normalization).
    {
        uint4* ez = (uint4*)&Ebuf[0][0];
        const uint4 z = make_uint4(0u, 0u, 0u, 0u);
        for (int i2 = tid; i2 < 3024; i2 += BLK) ez[i2] = z;
        if (tid < 64) xs[tid] = inputs[b0 * 32 + tid] * 100.0f;
    }
    __syncthreads();

    // ---- P1: ALL early weight gathers, shared loads across slots ----------
    for (int idx = tid; idx < 216; idx += BLK) {
        int x = idx/36, d = (idx/6)%6, r = idx%6;
        int g0 = x + d*6 + r*36, g3 = x + d*216 + r*36;
        float a, c;
        a = SITE(0,1)[g0]; c = SITE(0,1)[g0+1296];
        CTf[0][idx]       = xs[2]  * a + xs[3]  * c;
        CTf[1][idx]       = xs[34] * a + xs[35] * c;
        a = SITE(0,2)[g0]; c = SITE(0,2)[g0+1296];
        CTf[0][216 + idx] = xs[4]  * a + xs[5]  * c;
        CTf[1][216 + idx] = xs[36] * a + xs[37] * c;
        a = SITE(3,1)[g3]; c = SITE(3,1)[g3+1296];
        CTf[0][432 + idx] = xs[26] * a + xs[27] * c;
        CTf[1][432 + idx] = xs[58] * a + xs[59] * c;
        a = SITE(3,2)[g3]; c = SITE(3,2)[g3+1296];
        CTf[0][648 + idx] = xs[28] * a + xs[29] * c;
        CTf[1][648 + idx] = xs[60] * a + xs[61] * c;
    }
    for (int idx = tid; idx < 36; idx += BLK) {
        int x = idx/6, d = idx%6;
        float a, c;
        a = SITE(0,3)[x + d*6];   c = SITE(0,3)[x + d*6 + 1296];
        CTf[0][864 + idx] = xs[6]  * a + xs[7]  * c;
        CTf[1][864 + idx] = xs[38] * a + xs[39] * c;
        a = SITE(3,3)[x + d*216]; c = SITE(3,3)[x + d*216 + 1296];
        CTf[0][900 + idx] = xs[30] * a + xs[31] * c;
        CTf[1][900 + idx] = xs[62] * a + xs[63] * c;
        int u = x, r = d;
        float a0 = SITE(0,0)[r*36 + u*6],   c0 = SITE(0,0)[r*36 + u*6 + 1296];
        float a3 = SITE(3,0)[u*216 + r*36], c3 = SITE(3,0)[u*216 + r*36 + 1296];
        Ebuf[0][u*56 + 6  + r] = f2b(xs[0]  * a0 + xs[1]  * c0);
        Ebuf[1][u*56 + 6  + r] = f2b(xs[32] * a0 + xs[33] * c0);
        Ebuf[0][u*56 + 18 + r] = f2b(xs[24] * a3 + xs[25] * c3);
        Ebuf[1][u*56 + 18 + r] = f2b(xs[56] * a3 + xs[57] * c3);
    }
    {   // T10 / T20 (K6 tiles [36][16], k>=6 zero)
        const float *s10 = SITE(1,0), *s20 = SITE(2,0);
        for (int idx = tid; idx < 576; idx += BLK) {
            int n = idx/16, k = idx%16;
            float v00 = 0.f, v01 = 0.f, v10 = 0.f, v11 = 0.f;
            if (k < 6) {
                int g = k*216 + (n/6)*6 + (n%6)*36;
                float a = s10[g], c = s10[g+1296];
                v00 = xs[8]  * a + xs[9]  * c;
                v01 = xs[40] * a + xs[41] * c;
                a = s20[g]; c = s20[g+1296];
                v10 = xs[16] * a + xs[17] * c;
                v11 = xs[48] * a + xs[49] * c;
            }
            Tk6[0][n*16 + k]       = f2b(v00);
            Tk6[1][n*16 + k]       = f2b(v01);
            Tk6[0][576 + n*16 + k] = f2b(v10);
            Tk6[1][576 + n*16 + k] = f2b(v11);
        }
    }
    {   // T11 -> TA ([36][48 valid], k>=36 zero)
        const float* s = SITE(1,1);
        for (int idx = tid; idx < 1728; idx += BLK) {
            int n = idx/48, k = idx%48;
            float v0 = 0.f, v1 = 0.f;
            if (k < 36) {
                int g = (k/6)*216 + (k%6) + (n/6)*6 + (n%6)*36;
                float a = s[g], c = s[g+1296];
                v0 = xs[10] * a + xs[11] * c;
                v1 = xs[42] * a + xs[43] * c;
            }
            TA[0][n*56 + k] = f2b(v0);
            TA[1][n*56 + k] = f2b(v1);
        }
    }
    for (int idx = tid; idx < 432; idx += BLK) {   // TBt k-pads 36..47 zero
        int n = idx/12, k = 36 + idx%12;
        TBt[0][n*56 + k] = 0;
        TBt[1][n*56 + k] = 0;
    }
    __syncthreads();

    // ---- P2: chain step1 (M=6), both slots --------------------------------
    for (int t2 = tid; t2 < 216; t2 += BLK) {
        int m = t2/36, n = t2%36;
        #pragma unroll
        for (int s = 0; s < 2; ++s) {
            float a0 = 0.f, a3 = 0.f;
            #pragma unroll
            for (int k = 0; k < 6; ++k) {
                a0 = fmaf(b2f(Ebuf[s][m*56 + 6  + k]), CTf[s][k*36 + n],       a0);
                a3 = fmaf(b2f(Ebuf[s][m*56 + 18 + k]), CTf[s][432 + k*36 + n], a3);
            }
            int o = (m*6 + n/6)*56 + n%6;
            Ebuf[s][o + 12] = f2b(a0);
            Ebuf[s][o + 24] = f2b(a3);
        }
    }
    __syncthreads();

    // ---- P3: chain step2 (M=36), both slots -------------------------------
    for (int t2 = tid; t2 < 1296; t2 += BLK) {
        int m = t2/36, n = t2%36;
        #pragma unroll
        for (int s = 0; s < 2; ++s) {
            float a0 = 0.f, a3 = 0.f;
            #pragma unroll
            for (int k = 0; k < 6; ++k) {
                a0 = fmaf(b2f(Ebuf[s][m*56 + 12 + k]), CTf[s][216 + k*36 + n], a0);
                a3 = fmaf(b2f(Ebuf[s][m*56 + 24 + k]), CTf[s][648 + k*36 + n], a3);
            }
            int o = (m*6 + n/6)*56 + n%6;
            Ebuf[s][o + 6]  = f2b(a0);
            Ebuf[s][o + 18] = f2b(a3);
        }
    }
    __syncthreads();

    // ---- P4: chain tails: band6 -> E0 (cols 0..5); band18 -> EBT bf16 -----
    for (int t2 = tid; t2 < 1296; t2 += BLK) {
        int m = t2/6, n = t2%6;
        #pragma unroll
        for (int s = 0; s < 2; ++s) {
            float a0 = 0.f, a3 = 0.f;
            #pragma unroll
            for (int k = 0; k < 6; ++k) {
                a0 = fmaf(b2f(Ebuf[s][m*56 + 6  + k]), CTf[s][864 + k*6 + n], a0);
                a3 = fmaf(b2f(Ebuf[s][m*56 + 18 + k]), CTf[s][900 + k*6 + n], a3);
            }
            Ebuf[s][((m % 36)*6 + n)*56 + m/36] = f2b(a0);     // E0 [(d1d2d3)][d0]
            TBt[s][((m % 6)*6 + n)*56 + m/6]    = f2b(a3);     // EBT [n=(d2d3)][k=(d0d1)]
        }
    }
    __syncthreads();

    // ================= row 1 =================
    ACC0();
    MFMA_PHASE(0, 1, 2, Tk6[0], 16);                             // P5: j=0 (T10)
    MFMA_PHASE(1, 1, 2, Tk6[1], 16);
    __syncthreads();
    SCATTER(0, 2, 36, EbS[((m%36)*6 + n/6)*56 + (m/36)*6 + n%6] = f2b(v));  // P6
    SCATTER(1, 2, 36, EbS[((m%36)*6 + n/6)*56 + (m/36)*6 + n%6] = f2b(v));
    {   // build T13 -> CTf overlay (rows 0..5, k-pads zero)
        const float* s = SITE(1,3);
        for (int idx = tid; idx < 288; idx += BLK) {
            int n = idx/48, k = idx%48;
            float v0 = 0.f, v1 = 0.f;
            if (k < 36) {
                int g = (k/6)*216 + (k%6) + n*6;
                float a = s[g], c = s[g+1296];
                v0 = xs[14] * a + xs[15] * c;
                v1 = xs[46] * a + xs[47] * c;
            }
            ((unsigned short*)CTf[0])[n*56 + k] = f2b(v0);
            ((unsigned short*)CTf[1])[n*56 + k] = f2b(v1);
        }
    }
    __syncthreads();
    ACC0();
    MFMA_PHASE(0, 3, 2, TA[0], 56);                              // P7: j=1 (T11)
    MFMA_PHASE(1, 3, 2, TA[1], 56);
    __syncthreads();
    SCATTER(0, 2, 36, EbS[((m%36)*6 + n/6)*56 + (m/36)*6 + n%6] = f2b(v));  // P8
    SCATTER(1, 2, 36, EbS[((m%36)*6 + n/6)*56 + (m/36)*6 + n%6] = f2b(v));
    {   // build T12 -> TA (T11 dead)
        const float* s = SITE(1,2);
        for (int idx = tid; idx < 1728; idx += BLK) {
            int n = idx/48, k = idx%48;
            float v0 = 0.f, v1 = 0.f;
            if (k < 36) {
                int g = (k/6)*216 + (k%6) + (n/6)*6 + (n%6)*36;
                float a = s[g], c = s[g+1296];
                v0 = xs[12] * a + xs[13] * c;
                v1 = xs[44] * a + xs[45] * c;
            }
            TA[0][n*56 + k] = f2b(v0);
            TA[1][n*56 + k] = f2b(v1);
        }
    }
    __syncthreads();
    ACC0();
    MFMA_PHASE(0, 3, 2, TA[0], 56);                              // P9: j=2 (T12)
    MFMA_PHASE(1, 3, 2, TA[1], 56);
    __syncthreads();
    SCATTER(0, 2, 36, EbS[((m%36)*6 + n/6)*56 + (m/36)*6 + n%6] = f2b(v));  // P10
    SCATTER(1, 2, 36, EbS[((m%36)*6 + n/6)*56 + (m/36)*6 + n%6] = f2b(v));
    {   // build T21 -> TA (T12 dead)
        const float* s = SITE(2,1);
        for (int idx = tid; idx < 1728; idx += BLK) {
            int n = idx/48, k = idx%48;
            float v0 = 0.f, v1 = 0.f;
            if (k < 36) {
                int g = (k/6)*216 + (k%6) + (n/6)*6 + (n%6)*36;
                float a = s[g], c = s[g+1296];
                v0 = xs[18] * a + xs[19] * c;
                v1 = xs[50] * a + xs[51] * c;
            }
            TA[0][n*56 + k] = f2b(v0);
            TA[1][n*56 + k] = f2b(v1);
        }
    }
    __syncthreads();
    ACC0();
    MFMA_PHASE(0, 3, 1, (unsigned short*)CTf[0], 56);            // P11: j=3 (T13)
    MFMA_PHASE(1, 3, 1, (unsigned short*)CTf[1], 56);
    __syncthreads();
    SCATTER(0, 1, 6, EbS[((m%36)*6 + n)*56 + m/36] = f2b(v));    // P12: env_top
    SCATTER(1, 1, 6, EbS[((m%36)*6 + n)*56 + m/36] = f2b(v));
    {   // build NT -> CTf overlay (T13 dead)
        const float* s = SITE(2,3);
        for (int idx = tid; idx < 288; idx += BLK) {
            int n = idx/48, k = idx%48;
            float v0 = 0.f, v1 = 0.f;
            if (k < 36) {
                int g = (k/6)*216 + (k%6)*6 + n;
                float a = s[g], c = s[g+1296];
                v0 = xs[22] * a + xs[23] * c;
                v1 = xs[54] * a + xs[55] * c;
            }
            ((unsigned short*)CTf[0])[n*56 + k] = f2b(v0);
            ((unsigned short*)CTf[1])[n*56 + k] = f2b(v1);
        }
    }
    __syncthreads();

    // ================= row 2 =================
    ACC0();
    MFMA_PHASE(0, 1, 2, (Tk6[0] + 576), 16);                     // P13: j=0 (T20)
    MFMA_PHASE(1, 1, 2, (Tk6[1] + 576), 16);
    __syncthreads();
    SCATTER(0, 2, 36, EbS[((m%36)*6 + n/6)*56 + (m/36)*6 + n%6] = f2b(v));  // P14
    SCATTER(1, 2, 36, EbS[((m%36)*6 + n/6)*56 + (m/36)*6 + n%6] = f2b(v));
    __syncthreads();
    ACC0();
    MFMA_PHASE(0, 3, 2, TA[0], 56);                              // P15: j=1 (T21)
    MFMA_PHASE(1, 3, 2, TA[1], 56);
    __syncthreads();
    SCATTER(0, 2, 36, EbS[((m/6)*6 + n%6)*56 + (m%6)*6 + n/6] = f2b(v));    // P16
    SCATTER(1, 2, 36, EbS[((m/6)*6 + n%6)*56 + (m%6)*6 + n/6] = f2b(v));
    __syncthreads();
    ACC0();
    MFMA_PHASE(0, 3, 2, TBt[0], 56);                             // P17: R = S_pre x EB
    MFMA_PHASE(1, 3, 2, TBt[1], 56);
    __syncthreads();
    SCATTER(0, 2, 36, EbS[((m/36)*36 + (m%6)*6 + n/6)*56 + ((m/6)%6)*6 + n%6] = f2b(v)); // P18
    SCATTER(1, 2, 36, EbS[((m/36)*36 + (m%6)*6 + n/6)*56 + ((m/6)%6)*6 + n%6] = f2b(v));
    __syncthreads();
    ACC0();
    MFMA_PHASE(0, 3, 1, (unsigned short*)CTf[0], 56);            // P19a: T1 (NT)
    MFMA_PHASE(1, 3, 1, (unsigned short*)CTf[1], 56);
    __syncthreads();   // all Ebuf frag reads done before T1 overlays it
    SCATTER(0, 1, 6, T1S[m*6 + n] = v);                          // P19b
    SCATTER(1, 1, 6, T1S[m*6 + n] = v);
    __syncthreads();

    // ---- P20: out[o] = sum T1 * (x20*C0 + x21*C1), pepsc read once --------
    float part[2][10];
    #pragma unroll
    for (int s = 0; s < 2; ++s)
        #pragma unroll
        for (int o = 0; o < 10; ++o) part[s][o] = 0.f;
    {
        const float* T10p = (const float*)Ebuf[0];
        const float* T11p = (const float*)Ebuf[1];
        for (int c = tid; c < 1296; c += BLK) {
            int u2 = c / 216, r2 = (c / 36) % 6, d2 = (c / 6) % 6, r1 = c % 6;
            int e6 = u2*216 + r1*36 + d2*6 + r2;
            float t10 = T10p[e6], t11 = T11p[e6];
            #pragma unroll
            for (int o = 0; o < 10; ++o) {
                float c0 = pepsc[o * 1296 + c];
                float c1 = pepsc[(10 + o) * 1296 + c];
                part[0][o] = fmaf(t10, xs[20] * c0 + xs[21] * c1, part[0][o]);
                part[1][o] = fmaf(t11, xs[52] * c0 + xs[53] * c1, part[1][o]);
            }
        }
    }
    #pragma unroll
    for (int off = 32; off >= 1; off >>= 1)
        #pragma unroll
        for (int s = 0; s < 2; ++s)
            #pragma unroll
            for (int o = 0; o < 10; ++o)
                part[s][o] += __shfl_down(part[s][o], off, 64);
    if (lid == 0) {
        #pragma unroll
        for (int s = 0; s < 2; ++s)
            #pragma unroll
            for (int o = 0; o < 10; ++o)
                red[s * 52 + wid * 10 + o] = part[s][o];
    }
    __syncthreads();
    {
        int s = tid >> 7, t = tid & 127;
        if (t < 10)
            red[s * 52 + 40 + t] = red[s * 52 + t] + red[s * 52 + 10 + t]
                                 + red[s * 52 + 20 + t] + red[s * 52 + 30 + t];
        __syncthreads();
        if (t == 0) {
            float n2 = 0.f;
            #pragma unroll
            for (int o = 0; o < 10; ++o)
                n2 += red[s * 52 + 40 + o] * red[s * 52 + 40 + o];
            red[s * 52 + 50] = 1.0f / sqrtf(n2);
        }
        __syncthreads();
        if (t < 10) out[(b0 + s) * 10 + t] = red[s * 52 + 40 + t] * red[s * 52 + 50];
    }
}

extern "C" void kernel_launch(void* const* d_in, const int* in_sizes, int n_in,
                              void* d_out, int out_size, void* d_ws, size_t ws_size,
                              hipStream_t stream) {
    const float* inputs = (const float*)d_in[0];   // (B,4,4,2) f32
    const float* peps   = (const float*)d_in[1];   // (4,4,2,6,6,6,6) f32
    const float* pepsc  = (const float*)d_in[2];   // (2,10,6,6,6,6) f32
    float* outp = (float*)d_out;                   // (B,10) f32
    const int B = in_sizes[0] / 32;
    peps_fused<<<dim3(B / 2), dim3(BLK), 0, stream>>>(inputs, peps, pepsc, outp);
}